// Round 1
// baseline (439.737 us; speedup 1.0000x reference)
//
#include <hip/hip_runtime.h>

// AGCRNCell on gfx950.
// Shapes: B=32, N=2048, DIM_IN=2, HIDDEN=64, C=66, CHEB_K=3, F = 32*66 = 2112 (pad 2176).
// Pipeline:
//   S = softmax(relu(E E^T))                        [2048,2048] bf16
//   T0 = X0^T (f-major, k=node contiguous)          [2176,2048] bf16
//   T1 = (A@X0)^T, T2 = (2A@X1 - X0)^T              via gemm epilogues
//   G  = [x0|x1|x2] rows (k-contig, K padded 224)   [65536,224] bf16
//   ZR = sigmoid(G @ Wg + bg)                       [65536,128] f32
//   repeat with candidate (x, z*state) -> update GEMM fuses tanh + h = r*s + (1-r)*hc

typedef __bf16 bf16x8 __attribute__((ext_vector_type(8)));
typedef __bf16 bf16x4 __attribute__((ext_vector_type(4)));
typedef float  f32x4  __attribute__((ext_vector_type(4)));

#define GLB(p) ((__attribute__((address_space(1))) void*)(void*)(p))
#define LDS(p) ((__attribute__((address_space(3))) void*)(p))

// ---------------- supports: S[n][m] = softmax_m(relu(E[n]·E[m])) ----------------
__global__ void supports_kernel(const float* __restrict__ E, __bf16* __restrict__ S) {
    const int n = blockIdx.x;
    const int t = threadIdx.x;            // 256
    const int l = t & 63, w = t >> 6;
    float en[10];
#pragma unroll
    for (int i = 0; i < 10; ++i) en[i] = E[n * 10 + i];
    float vals[8];
    float mx = 0.f;
#pragma unroll
    for (int q = 0; q < 8; ++q) {
        const int m = q * 256 + t;
        const float* em = E + (size_t)m * 10;
        float d = 0.f;
#pragma unroll
        for (int i = 0; i < 10; ++i) d += en[i] * em[i];
        d = fmaxf(d, 0.f);
        vals[q] = d;
        mx = fmaxf(mx, d);
    }
#pragma unroll
    for (int off = 32; off; off >>= 1) mx = fmaxf(mx, __shfl_xor(mx, off));
    __shared__ float sm[4], ss[4];
    if (l == 0) sm[w] = mx;
    __syncthreads();
    mx = fmaxf(fmaxf(sm[0], sm[1]), fmaxf(sm[2], sm[3]));
    float sum = 0.f;
#pragma unroll
    for (int q = 0; q < 8; ++q) { vals[q] = __expf(vals[q] - mx); sum += vals[q]; }
#pragma unroll
    for (int off = 32; off; off >>= 1) sum += __shfl_xor(sum, off);
    if (l == 0) ss[w] = sum;
    __syncthreads();
    sum = ss[0] + ss[1] + ss[2] + ss[3];
    const float inv = 1.f / sum;
#pragma unroll
    for (int q = 0; q < 8; ++q) S[(size_t)n * 2048 + q * 256 + t] = (__bf16)(vals[q] * inv);
}

// ---------------- build T (f-major transposed input), f = b*66+c ----------------
// zr == nullptr: T = concat(x, state)^T ; else T = concat(x, z*state)^T (z = zr cols 0..63)
__global__ void build_t(const float* __restrict__ x, const float* __restrict__ st,
                        const float* __restrict__ zr, __bf16* __restrict__ T) {
    const int f = blockIdx.x;             // 0..2175
    const int n0 = threadIdx.x * 8;
    bf16x8 v;
    if (f >= 2112) {
#pragma unroll
        for (int j = 0; j < 8; ++j) v[j] = (__bf16)0.f;
        *(bf16x8*)&T[(size_t)f * 2048 + n0] = v;
        return;
    }
    const int b = f / 66, c = f % 66;
    const size_t mb = (size_t)b * 2048;
    if (c < 2) {
#pragma unroll
        for (int j = 0; j < 8; ++j) v[j] = (__bf16)x[(mb + n0 + j) * 2 + c];
    } else {
        const int cc = c - 2;
#pragma unroll
        for (int j = 0; j < 8; ++j) {
            float s = st[(mb + n0 + j) * 64 + cc];
            if (zr) s *= zr[(mb + n0 + j) * 128 + cc];
            v[j] = (__bf16)s;
        }
    }
    *(bf16x8*)&T[(size_t)f * 2048 + n0] = v;
}

// ---------------- build G[m=(b,n)][k=jj*66+c], K padded to 224 ----------------
__global__ void build_g(const __bf16* __restrict__ T0, const __bf16* __restrict__ T1,
                        const __bf16* __restrict__ T2, __bf16* __restrict__ G) {
    const int id = blockIdx.x * 256 + threadIdx.x;   // 65536*28 tasks
    const int m = id / 28, kc8 = id % 28;
    const int b = m >> 11, n = m & 2047;
    const int k0 = kc8 * 8;
    bf16x8 v;
#pragma unroll
    for (int j = 0; j < 8; ++j) {
        const int k = k0 + j;
        __bf16 val = (__bf16)0.f;
        if (k < 198) {
            int c; const __bf16* T;
            if (k < 66)       { T = T0; c = k; }
            else if (k < 132) { T = T1; c = k - 66; }
            else              { T = T2; c = k - 132; }
            val = T[(size_t)(b * 66 + c) * 2048 + n];
        }
        v[j] = val;
    }
    *(bf16x8*)&G[(size_t)m * 224 + k0] = v;
}

// ---------------- build W^T padded: WT[o][k] = (k<198 && o<Nout) ? W[k][o] : 0 ----------------
__global__ void build_wt(const float* __restrict__ W, __bf16* __restrict__ WT, int Nout) {
    const int id = blockIdx.x * 256 + threadIdx.x;   // 128*224
    if (id >= 128 * 224) return;
    const int o = id / 224, k = id % 224;
    WT[id] = (o < Nout && k < 198) ? (__bf16)W[(size_t)k * Nout + o] : (__bf16)0.f;
}

// ---------------- GEMM: C[M][Ncols] = A[M][K] @ B, B given as Bt[Ncols][K] ----------------
// 128x128 tile, BK=32, 256 threads = 4 waves (2x2), 4x4 mfma 16x16x32 per wave.
// epi: 0 store outT[col][row] bf16 (ld 2048)
//      1 outT[col][row] = bf16(2*acc - subT[col][row])
//      2 outF[row*128+col] = sigmoid(acc + bias[col])
//      3 (col<64) outF[row*64+col] = r*state + (1-r)*tanh(acc+bias[col]), r = zrbuf[row*128+64+col]
__global__ __launch_bounds__(256, 2)
void gemm_bt(const __bf16* __restrict__ A, int lda,
             const __bf16* __restrict__ Bt, int ldb,
             int K, int epi,
             __bf16* __restrict__ outT, const __bf16* __restrict__ subT,
             float* __restrict__ outF, const float* __restrict__ bias,
             const float* __restrict__ zrbuf, const float* __restrict__ state) {
    __shared__ __bf16 As[128 * 32];
    __shared__ __bf16 Bs[128 * 32];
    const int t = threadIdx.x;
    const int l = t & 63, w = t >> 6;
    const int wr = w >> 1, wc = w & 1;
    const int m0 = blockIdx.x * 128;
    const int n0 = blockIdx.y * 128;
    const int lm = l & 15;
    const int lk = (l >> 4) * 8;
    const int srow = t >> 2;
    const int skc = (t & 3) * 8;

    f32x4 acc[4][4];
#pragma unroll
    for (int i = 0; i < 4; ++i)
#pragma unroll
        for (int j = 0; j < 4; ++j) acc[i][j] = (f32x4)0.f;

    const __bf16* Ab = A + (size_t)(m0 + srow) * lda + skc;
    const __bf16* Bb = Bt + (size_t)(n0 + srow) * ldb + skc;
    const size_t a64 = (size_t)64 * lda;
    const size_t b64 = (size_t)64 * ldb;
    __bf16* AsD = As + t * 8;
    __bf16* BsD = Bs + t * 8;

    for (int k0 = 0; k0 < K; k0 += 32) {
        __builtin_amdgcn_global_load_lds(GLB(Ab + k0),       LDS(AsD),        16, 0, 0);
        __builtin_amdgcn_global_load_lds(GLB(Ab + k0 + a64), LDS(AsD + 2048), 16, 0, 0);
        __builtin_amdgcn_global_load_lds(GLB(Bb + k0),       LDS(BsD),        16, 0, 0);
        __builtin_amdgcn_global_load_lds(GLB(Bb + k0 + b64), LDS(BsD + 2048), 16, 0, 0);
        __syncthreads();
        bf16x8 af[4], bfr[4];
#pragma unroll
        for (int i = 0; i < 4; ++i)
            af[i] = *(const bf16x8*)(As + (wr * 64 + i * 16 + lm) * 32 + lk);
#pragma unroll
        for (int j = 0; j < 4; ++j)
            bfr[j] = *(const bf16x8*)(Bs + (wc * 64 + j * 16 + lm) * 32 + lk);
#pragma unroll
        for (int i = 0; i < 4; ++i)
#pragma unroll
            for (int j = 0; j < 4; ++j)
                acc[i][j] = __builtin_amdgcn_mfma_f32_16x16x32_bf16(af[i], bfr[j], acc[i][j], 0, 0, 0);
        __syncthreads();
    }

    // epilogue: C row = m (quad*4+reg), col = lane&15  [verified m89 layout]
    const int rb0 = m0 + wr * 64 + (l >> 4) * 4;
    const int cb0 = n0 + wc * 64 + lm;
#pragma unroll
    for (int i = 0; i < 4; ++i) {
        const int rbase = rb0 + i * 16;
#pragma unroll
        for (int j = 0; j < 4; ++j) {
            const int c = cb0 + j * 16;
            f32x4 v = acc[i][j];
            if (epi == 0) {
                bf16x4 pk;
#pragma unroll
                for (int r = 0; r < 4; ++r) pk[r] = (__bf16)v[r];
                *(bf16x4*)&outT[(size_t)c * 2048 + rbase] = pk;
            } else if (epi == 1) {
                bf16x4 s = *(const bf16x4*)&subT[(size_t)c * 2048 + rbase];
                bf16x4 pk;
#pragma unroll
                for (int r = 0; r < 4; ++r) pk[r] = (__bf16)(2.f * v[r] - (float)s[r]);
                *(bf16x4*)&outT[(size_t)c * 2048 + rbase] = pk;
            } else if (epi == 2) {
                const float bb = bias[c];
#pragma unroll
                for (int r = 0; r < 4; ++r) {
                    float xx = fminf(fmaxf(v[r] + bb, -30.f), 30.f);
                    outF[(size_t)(rbase + r) * 128 + c] = 1.f / (1.f + __expf(-xx));
                }
            } else {
                if (c < 64) {
                    const float bb = bias[c];
#pragma unroll
                    for (int r = 0; r < 4; ++r) {
                        const int m = rbase + r;
                        float xx = fminf(fmaxf(v[r] + bb, -15.f), 15.f);
                        float e = __expf(2.f * xx);
                        float hc = (e - 1.f) / (e + 1.f);
                        float rr = zrbuf[(size_t)m * 128 + 64 + c];
                        float s = state[(size_t)m * 64 + c];
                        outF[(size_t)m * 64 + c] = rr * s + (1.f - rr) * hc;
                    }
                }
            }
        }
    }
}

extern "C" void kernel_launch(void* const* d_in, const int* in_sizes, int n_in,
                              void* d_out, int out_size, void* d_ws, size_t ws_size,
                              hipStream_t stream) {
    (void)in_sizes; (void)n_in; (void)out_size; (void)ws_size;
    const float* x  = (const float*)d_in[0];
    const float* st = (const float*)d_in[1];
    const float* E  = (const float*)d_in[2];
    const float* Wg = (const float*)d_in[3];
    const float* bg = (const float*)d_in[4];
    const float* Wu = (const float*)d_in[5];
    const float* bu = (const float*)d_in[6];
    float* out = (float*)d_out;

    char* p = (char*)d_ws;
    __bf16* S   = (__bf16*)p; p += (size_t)2048 * 2048 * 2;   // 8.4 MB
    __bf16* T0  = (__bf16*)p; p += (size_t)2176 * 2048 * 2;   // 8.9 MB
    __bf16* T1  = (__bf16*)p; p += (size_t)2176 * 2048 * 2;
    __bf16* T2  = (__bf16*)p; p += (size_t)2176 * 2048 * 2;
    __bf16* G   = (__bf16*)p; p += (size_t)65536 * 224 * 2;   // 29.4 MB
    float*  ZR  = (float*) p; p += (size_t)65536 * 128 * 4;   // 33.6 MB
    __bf16* WTg = (__bf16*)p; p += 128 * 224 * 2;
    __bf16* WTu = (__bf16*)p; p += 128 * 224 * 2;             // total ~94 MB

    build_wt<<<112, 256, 0, stream>>>(Wg, WTg, 128);
    build_wt<<<112, 256, 0, stream>>>(Wu, WTu, 64);
    supports_kernel<<<2048, 256, 0, stream>>>(E, S);

    // gate phase
    build_t<<<2176, 256, 0, stream>>>(x, st, nullptr, T0);
    gemm_bt<<<dim3(16, 17), 256, 0, stream>>>(S, 2048, T0, 2048, 2048, 0, T1, nullptr, nullptr, nullptr, nullptr, nullptr);
    gemm_bt<<<dim3(16, 17), 256, 0, stream>>>(S, 2048, T1, 2048, 2048, 1, T2, T0, nullptr, nullptr, nullptr, nullptr);
    build_g<<<7168, 256, 0, stream>>>(T0, T1, T2, G);
    gemm_bt<<<dim3(512, 1), 256, 0, stream>>>(G, 224, WTg, 224, 224, 2, nullptr, nullptr, ZR, bg, nullptr, nullptr);

    // update phase
    build_t<<<2176, 256, 0, stream>>>(x, st, ZR, T0);
    gemm_bt<<<dim3(16, 17), 256, 0, stream>>>(S, 2048, T0, 2048, 2048, 0, T1, nullptr, nullptr, nullptr, nullptr, nullptr);
    gemm_bt<<<dim3(16, 17), 256, 0, stream>>>(S, 2048, T1, 2048, 2048, 1, T2, T0, nullptr, nullptr, nullptr, nullptr);
    build_g<<<7168, 256, 0, stream>>>(T0, T1, T2, G);
    gemm_bt<<<dim3(512, 1), 256, 0, stream>>>(G, 224, WTu, 224, 224, 3, nullptr, nullptr, out, bu, ZR, st);
}

// Round 2
// 375.901 us; speedup vs baseline: 1.1698x; 1.1698x over previous
//
#include <hip/hip_runtime.h>

// AGCRNCell on gfx950.  B=32, N=2048, C=66, CHEB_K=3, F=2112 (pad 2176).
// S = softmax(relu(E E^T)); chained S@X GEMMs in T-layout (f-major, node-contig);
// LDS-swizzled transpose T->G [65536 x 224]; W-GEMMs with fused sigmoid / tanh+gate.
// R2: 128x64 GEMM tiles (544 blocks -> ~2 blocks/CU, occupancy was the R1 limiter);
//     build_g replaced by coalesced LDS transpose.

typedef __bf16 bf16x8 __attribute__((ext_vector_type(8)));
typedef __bf16 bf16x4 __attribute__((ext_vector_type(4)));
typedef float  f32x4  __attribute__((ext_vector_type(4)));

#define GLB(p) ((__attribute__((address_space(1))) void*)(void*)(p))
#define LDS(p) ((__attribute__((address_space(3))) void*)(p))

// ---------------- supports: S[n][m] = softmax_m(relu(E[n]·E[m])) ----------------
__global__ void supports_kernel(const float* __restrict__ E, __bf16* __restrict__ S) {
    const int n = blockIdx.x;
    const int t = threadIdx.x;            // 256
    const int l = t & 63, w = t >> 6;
    float en[10];
#pragma unroll
    for (int i = 0; i < 10; ++i) en[i] = E[n * 10 + i];
    float vals[8];
    float mx = 0.f;
#pragma unroll
    for (int q = 0; q < 8; ++q) {
        const int m = q * 256 + t;
        const float* em = E + (size_t)m * 10;
        float d = 0.f;
#pragma unroll
        for (int i = 0; i < 10; ++i) d += en[i] * em[i];
        d = fmaxf(d, 0.f);
        vals[q] = d;
        mx = fmaxf(mx, d);
    }
#pragma unroll
    for (int off = 32; off; off >>= 1) mx = fmaxf(mx, __shfl_xor(mx, off));
    __shared__ float sm[4], ss[4];
    if (l == 0) sm[w] = mx;
    __syncthreads();
    mx = fmaxf(fmaxf(sm[0], sm[1]), fmaxf(sm[2], sm[3]));
    float sum = 0.f;
#pragma unroll
    for (int q = 0; q < 8; ++q) { vals[q] = __expf(vals[q] - mx); sum += vals[q]; }
#pragma unroll
    for (int off = 32; off; off >>= 1) sum += __shfl_xor(sum, off);
    if (l == 0) ss[w] = sum;
    __syncthreads();
    sum = ss[0] + ss[1] + ss[2] + ss[3];
    const float inv = 1.f / sum;
#pragma unroll
    for (int q = 0; q < 8; ++q) S[(size_t)n * 2048 + q * 256 + t] = (__bf16)(vals[q] * inv);
}

// ---------------- build T (f-major transposed input), f = b*66+c ----------------
__global__ void build_t(const float* __restrict__ x, const float* __restrict__ st,
                        const float* __restrict__ zr, __bf16* __restrict__ T) {
    const int f = blockIdx.x;             // 0..2175
    const int n0 = threadIdx.x * 8;
    bf16x8 v;
    if (f >= 2112) {
#pragma unroll
        for (int j = 0; j < 8; ++j) v[j] = (__bf16)0.f;
        *(bf16x8*)&T[(size_t)f * 2048 + n0] = v;
        return;
    }
    const int b = f / 66, c = f % 66;
    const size_t mb = (size_t)b * 2048;
    if (c < 2) {
#pragma unroll
        for (int j = 0; j < 8; ++j) v[j] = (__bf16)x[(mb + n0 + j) * 2 + c];
    } else {
        const int cc = c - 2;
#pragma unroll
        for (int j = 0; j < 8; ++j) {
            float s = st[(mb + n0 + j) * 64 + cc];
            if (zr) s *= zr[(mb + n0 + j) * 128 + cc];
            v[j] = (__bf16)s;
        }
    }
    *(bf16x8*)&T[(size_t)f * 2048 + n0] = v;
}

// ---------------- transpose T-layout -> G[m=(b,n)][k], k padded to 224 ----------------
// LDS tile 128 m-rows x 256 k-stride, XOR granule swizzle:
//   elem(m,k) = m*256 + ((k>>3) ^ (m>>3))*8 + (k&7)
// Phase 1: coalesced bf16x8 reads of T columns, scalar LDS writes (~4-way conflicts).
// Phase 2: conflict-free ds_read_b128, coalesced bf16x8 G-row stores.
__global__ __launch_bounds__(256, 2)
void transpose_g(const __bf16* __restrict__ T0, const __bf16* __restrict__ T1,
                 const __bf16* __restrict__ T2, __bf16* __restrict__ G) {
    __shared__ __bf16 Ls[128 * 256];     // 64 KB
    const int b  = blockIdx.x >> 4;      // 0..31
    const int n0 = (blockIdx.x & 15) << 7;
    const int t = threadIdx.x;
#pragma unroll
    for (int r = 0; r < 14; ++r) {       // 224 k x 16 segs
        const int task = r * 256 + t;
        const int k = task >> 4, seg = task & 15;
        bf16x8 v;
        if (k < 198) {
            const __bf16* T; int c;
            if (k < 66)       { T = T0; c = k; }
            else if (k < 132) { T = T1; c = k - 66; }
            else              { T = T2; c = k - 132; }
            v = *(const bf16x8*)&T[(size_t)(b * 66 + c) * 2048 + n0 + seg * 8];
        } else {
#pragma unroll
            for (int j = 0; j < 8; ++j) v[j] = (__bf16)0.f;
        }
        const int base = seg * 8 * 256 + (((k >> 3) ^ seg) << 3) + (k & 7);
#pragma unroll
        for (int j = 0; j < 8; ++j) Ls[base + j * 256] = v[j];
    }
    __syncthreads();
#pragma unroll
    for (int r = 0; r < 16; ++r) {       // 128 m x 32 chunks (28 real)
        const int task = r * 256 + t;
        const int m = task >> 5, c8 = task & 31;
        if (c8 < 28) {
            bf16x8 w = *(const bf16x8*)&Ls[m * 256 + ((c8 ^ (m >> 3)) << 3)];
            *(bf16x8*)&G[(size_t)(b * 2048 + n0 + m) * 224 + c8 * 8] = w;
        }
    }
}

// ---------------- build W^T padded: WT[o][k] = (k<198 && o<Nout) ? W[k][o] : 0 ----------------
__global__ void build_wt(const float* __restrict__ W, __bf16* __restrict__ WT, int Nout) {
    const int id = blockIdx.x * 256 + threadIdx.x;   // 128*224
    if (id >= 128 * 224) return;
    const int o = id / 224, k = id % 224;
    WT[id] = (o < Nout && k < 198) ? (__bf16)W[(size_t)k * Nout + o] : (__bf16)0.f;
}

// ---------------- GEMM: C[M][Ncols] = A[M][K] @ B, B given as Bt[Ncols][K] ----------------
// 128x64 tile, BK=32, 256 threads = 4 waves (2x2), wave tile 64x32 = 4x2 mfma 16x16x32.
// epi: 0 outT[col][row] = bf16(acc)            (ld 2048)
//      1 outT[col][row] = bf16(2*acc - subT[col][row])
//      2 outF[row*128+col] = sigmoid(acc + bias[col])
//      3 (col<64) outF[row*64+col] = r*state + (1-r)*tanh(acc+bias[col]), r = zrbuf[row*128+64+col]
__global__ __launch_bounds__(256, 2)
void gemm_bt(const __bf16* __restrict__ A, int lda,
             const __bf16* __restrict__ Bt, int ldb,
             int K, int epi,
             __bf16* __restrict__ outT, const __bf16* __restrict__ subT,
             float* __restrict__ outF, const float* __restrict__ bias,
             const float* __restrict__ zrbuf, const float* __restrict__ state) {
    __shared__ __bf16 As[128 * 32];
    __shared__ __bf16 Bs[64 * 32];
    const int t = threadIdx.x;
    const int l = t & 63, w = t >> 6;
    const int wr = w >> 1, wc = w & 1;
    const int m0 = blockIdx.x * 128;
    const int n0 = blockIdx.y * 64;
    const int lm = l & 15;
    const int lk = (l >> 4) * 8;
    const int srow = t >> 2;             // 0..63
    const int skc = (t & 3) * 8;

    f32x4 acc[4][2];
#pragma unroll
    for (int i = 0; i < 4; ++i)
#pragma unroll
        for (int j = 0; j < 2; ++j) acc[i][j] = (f32x4)0.f;

    const __bf16* Ab = A + (size_t)(m0 + srow) * lda + skc;
    const __bf16* Bb = Bt + (size_t)(n0 + srow) * ldb + skc;
    const size_t a64 = (size_t)64 * lda;
    __bf16* AsD = As + t * 8;
    __bf16* BsD = Bs + t * 8;

    for (int k0 = 0; k0 < K; k0 += 32) {
        __builtin_amdgcn_global_load_lds(GLB(Ab + k0),       LDS(AsD),        16, 0, 0);
        __builtin_amdgcn_global_load_lds(GLB(Ab + k0 + a64), LDS(AsD + 2048), 16, 0, 0);
        __builtin_amdgcn_global_load_lds(GLB(Bb + k0),       LDS(BsD),        16, 0, 0);
        __syncthreads();
        bf16x8 af[4], bfr[2];
#pragma unroll
        for (int i = 0; i < 4; ++i)
            af[i] = *(const bf16x8*)(As + (wr * 64 + i * 16 + lm) * 32 + lk);
#pragma unroll
        for (int j = 0; j < 2; ++j)
            bfr[j] = *(const bf16x8*)(Bs + (wc * 32 + j * 16 + lm) * 32 + lk);
#pragma unroll
        for (int i = 0; i < 4; ++i)
#pragma unroll
            for (int j = 0; j < 2; ++j)
                acc[i][j] = __builtin_amdgcn_mfma_f32_16x16x32_bf16(af[i], bfr[j], acc[i][j], 0, 0, 0);
        __syncthreads();
    }

    // epilogue: C row = m (quad*4+reg), col = lane&15  [verified m89 layout]
    const int rb0 = m0 + wr * 64 + (l >> 4) * 4;
    const int cb0 = n0 + wc * 32 + lm;
#pragma unroll
    for (int i = 0; i < 4; ++i) {
        const int rbase = rb0 + i * 16;
#pragma unroll
        for (int j = 0; j < 2; ++j) {
            const int c = cb0 + j * 16;
            f32x4 v = acc[i][j];
            if (epi == 0) {
                bf16x4 pk;
#pragma unroll
                for (int r = 0; r < 4; ++r) pk[r] = (__bf16)v[r];
                *(bf16x4*)&outT[(size_t)c * 2048 + rbase] = pk;
            } else if (epi == 1) {
                bf16x4 s = *(const bf16x4*)&subT[(size_t)c * 2048 + rbase];
                bf16x4 pk;
#pragma unroll
                for (int r = 0; r < 4; ++r) pk[r] = (__bf16)(2.f * v[r] - (float)s[r]);
                *(bf16x4*)&outT[(size_t)c * 2048 + rbase] = pk;
            } else if (epi == 2) {
                const float bb = bias[c];
#pragma unroll
                for (int r = 0; r < 4; ++r) {
                    float xx = fminf(fmaxf(v[r] + bb, -30.f), 30.f);
                    outF[(size_t)(rbase + r) * 128 + c] = 1.f / (1.f + __expf(-xx));
                }
            } else {
                if (c < 64) {
                    const float bb = bias[c];
#pragma unroll
                    for (int r = 0; r < 4; ++r) {
                        const int m = rbase + r;
                        float xx = fminf(fmaxf(v[r] + bb, -15.f), 15.f);
                        float e = __expf(2.f * xx);
                        float hc = (e - 1.f) / (e + 1.f);
                        float rr = zrbuf[(size_t)m * 128 + 64 + c];
                        float s = state[(size_t)m * 64 + c];
                        outF[(size_t)m * 64 + c] = rr * s + (1.f - rr) * hc;
                    }
                }
            }
        }
    }
}

extern "C" void kernel_launch(void* const* d_in, const int* in_sizes, int n_in,
                              void* d_out, int out_size, void* d_ws, size_t ws_size,
                              hipStream_t stream) {
    (void)in_sizes; (void)n_in; (void)out_size; (void)ws_size;
    const float* x  = (const float*)d_in[0];
    const float* st = (const float*)d_in[1];
    const float* E  = (const float*)d_in[2];
    const float* Wg = (const float*)d_in[3];
    const float* bg = (const float*)d_in[4];
    const float* Wu = (const float*)d_in[5];
    const float* bu = (const float*)d_in[6];
    float* out = (float*)d_out;

    char* p = (char*)d_ws;
    __bf16* S   = (__bf16*)p; p += (size_t)2048 * 2048 * 2;
    __bf16* T0  = (__bf16*)p; p += (size_t)2176 * 2048 * 2;
    __bf16* T1  = (__bf16*)p; p += (size_t)2176 * 2048 * 2;
    __bf16* T2  = (__bf16*)p; p += (size_t)2176 * 2048 * 2;
    __bf16* G   = (__bf16*)p; p += (size_t)65536 * 224 * 2;
    float*  ZR  = (float*) p; p += (size_t)65536 * 128 * 4;
    __bf16* WTg = (__bf16*)p; p += 128 * 224 * 2;
    __bf16* WTu = (__bf16*)p; p += 128 * 224 * 2;

    build_wt<<<112, 256, 0, stream>>>(Wg, WTg, 128);
    build_wt<<<112, 256, 0, stream>>>(Wu, WTu, 64);
    supports_kernel<<<2048, 256, 0, stream>>>(E, S);

    // gate phase
    build_t<<<2176, 256, 0, stream>>>(x, st, nullptr, T0);
    gemm_bt<<<dim3(16, 34), 256, 0, stream>>>(S, 2048, T0, 2048, 2048, 0, T1, nullptr, nullptr, nullptr, nullptr, nullptr);
    gemm_bt<<<dim3(16, 34), 256, 0, stream>>>(S, 2048, T1, 2048, 2048, 1, T2, T0, nullptr, nullptr, nullptr, nullptr);
    transpose_g<<<512, 256, 0, stream>>>(T0, T1, T2, G);
    gemm_bt<<<dim3(512, 2), 256, 0, stream>>>(G, 224, WTg, 224, 224, 2, nullptr, nullptr, ZR, bg, nullptr, nullptr);

    // update phase
    build_t<<<2176, 256, 0, stream>>>(x, st, ZR, T0);
    gemm_bt<<<dim3(16, 34), 256, 0, stream>>>(S, 2048, T0, 2048, 2048, 0, T1, nullptr, nullptr, nullptr, nullptr, nullptr);
    gemm_bt<<<dim3(16, 34), 256, 0, stream>>>(S, 2048, T1, 2048, 2048, 1, T2, T0, nullptr, nullptr, nullptr, nullptr);
    transpose_g<<<512, 256, 0, stream>>>(T0, T1, T2, G);
    gemm_bt<<<dim3(512, 1), 256, 0, stream>>>(G, 224, WTu, 224, 224, 3, nullptr, nullptr, out, bu, ZR, st);
}

// Round 3
// 313.854 us; speedup vs baseline: 1.4011x; 1.1977x over previous
//
#include <hip/hip_runtime.h>

// AGCRNCell on gfx950.  B=32, N=2048, C=66, CHEB_K=3, F = 32*66 = 2112 (= 33*64, no pad).
// S = softmax(relu(E E^T)); chained S@X GEMMs in T-layout (f-major, node-contig);
// LDS transpose T->G [65536 x 224]; W-GEMMs with fused sigmoid / tanh+gate.
// R3: build_t -> LDS-tiled coalesced transpose (was 8x HBM over-fetch);
//     GEMM tiles 64x64 (1056 blocks ~ 4/CU; occupancy still the limiter at R1/R2);
//     ZR in bf16 (halves its traffic); F-padding removed (2112 % 64 == 0).

typedef __bf16 bf16x8 __attribute__((ext_vector_type(8)));
typedef __bf16 bf16x4 __attribute__((ext_vector_type(4)));
typedef float  f32x4  __attribute__((ext_vector_type(4)));

#define GLB(p) ((__attribute__((address_space(1))) void*)(void*)(p))
#define LDS(p) ((__attribute__((address_space(3))) void*)(p))

// ---------------- supports: S[n][m] = softmax_m(relu(E[n]·E[m])) ----------------
__global__ void supports_kernel(const float* __restrict__ E, __bf16* __restrict__ S) {
    const int n = blockIdx.x;
    const int t = threadIdx.x;            // 256
    const int l = t & 63, w = t >> 6;
    float en[10];
#pragma unroll
    for (int i = 0; i < 10; ++i) en[i] = E[n * 10 + i];
    float vals[8];
    float mx = 0.f;
#pragma unroll
    for (int q = 0; q < 8; ++q) {
        const int m = q * 256 + t;
        const float* em = E + (size_t)m * 10;
        float d = 0.f;
#pragma unroll
        for (int i = 0; i < 10; ++i) d += en[i] * em[i];
        d = fmaxf(d, 0.f);
        vals[q] = d;
        mx = fmaxf(mx, d);
    }
#pragma unroll
    for (int off = 32; off; off >>= 1) mx = fmaxf(mx, __shfl_xor(mx, off));
    __shared__ float sm[4], ss[4];
    if (l == 0) sm[w] = mx;
    __syncthreads();
    mx = fmaxf(fmaxf(sm[0], sm[1]), fmaxf(sm[2], sm[3]));
    float sum = 0.f;
#pragma unroll
    for (int q = 0; q < 8; ++q) { vals[q] = __expf(vals[q] - mx); sum += vals[q]; }
#pragma unroll
    for (int off = 32; off; off >>= 1) sum += __shfl_xor(sum, off);
    if (l == 0) ss[w] = sum;
    __syncthreads();
    sum = ss[0] + ss[1] + ss[2] + ss[3];
    const float inv = 1.f / sum;
#pragma unroll
    for (int q = 0; q < 8; ++q) S[(size_t)n * 2048 + q * 256 + t] = (__bf16)(vals[q] * inv);
}

// ---------------- build T via LDS transpose: T[f=b*66+c][n], coalesced both sides ----
// Block = (b, 128-node tile). Phase 1: float4 state-row reads (+bf16x4 zr) -> LDS
// tile [66][129] f32 (write banks (4q+n)%32 -> 2-way = free). Phase 2: read rows of
// the tile, pack bf16x8, coalesced column stores.
__global__ __launch_bounds__(256, 2)
void build_t2(const float* __restrict__ x, const float* __restrict__ st,
              const __bf16* __restrict__ zr, __bf16* __restrict__ T) {
    __shared__ float Ls[66 * 129];       // 34 KB
    const int b  = blockIdx.x >> 4;
    const int n0 = (blockIdx.x & 15) << 7;
    const int t = threadIdx.x;
    const size_t mb = (size_t)b * 2048 + n0;
    if (t < 128) {
        const float2 v = *(const float2*)&x[(mb + t) * 2];
        Ls[t] = v.x;
        Ls[129 + t] = v.y;
    }
#pragma unroll
    for (int r = 0; r < 8; ++r) {        // 128 rows x 16 col-quads
        const int task = r * 256 + t;
        const int q = task & 15, n = task >> 4;
        f32x4 v = *(const f32x4*)&st[(mb + n) * 64 + q * 4];
        if (zr) {
            const bf16x4 z = *(const bf16x4*)&zr[(mb + n) * 128 + q * 4];
#pragma unroll
            for (int j = 0; j < 4; ++j) v[j] *= (float)z[j];
        }
        const int base = (2 + q * 4) * 129 + n;
#pragma unroll
        for (int j = 0; j < 4; ++j) Ls[base + j * 129] = v[j];
    }
    __syncthreads();
#pragma unroll
    for (int r = 0; r < 5; ++r) {        // 66 c x 16 segs = 1056 tasks
        const int task = r * 256 + t;
        if (task < 1056) {
            const int c = task >> 4, seg = task & 15;
            const float* src = &Ls[c * 129 + seg * 8];
            bf16x8 o;
#pragma unroll
            for (int j = 0; j < 8; ++j) o[j] = (__bf16)src[j];
            *(bf16x8*)&T[(size_t)(b * 66 + c) * 2048 + n0 + seg * 8] = o;
        }
    }
}

// ---------------- transpose T-layout -> G[m=(b,n)][k], k padded to 224 ----------------
__global__ __launch_bounds__(256, 2)
void transpose_g(const __bf16* __restrict__ T0, const __bf16* __restrict__ T1,
                 const __bf16* __restrict__ T2, __bf16* __restrict__ G) {
    __shared__ __bf16 Ls[128 * 256];     // 64 KB
    const int b  = blockIdx.x >> 4;      // 0..31
    const int n0 = (blockIdx.x & 15) << 7;
    const int t = threadIdx.x;
#pragma unroll
    for (int r = 0; r < 14; ++r) {       // 224 k x 16 segs
        const int task = r * 256 + t;
        const int k = task >> 4, seg = task & 15;
        bf16x8 v;
        if (k < 198) {
            const __bf16* T; int c;
            if (k < 66)       { T = T0; c = k; }
            else if (k < 132) { T = T1; c = k - 66; }
            else              { T = T2; c = k - 132; }
            v = *(const bf16x8*)&T[(size_t)(b * 66 + c) * 2048 + n0 + seg * 8];
        } else {
#pragma unroll
            for (int j = 0; j < 8; ++j) v[j] = (__bf16)0.f;
        }
        const int base = seg * 8 * 256 + (((k >> 3) ^ seg) << 3) + (k & 7);
#pragma unroll
        for (int j = 0; j < 8; ++j) Ls[base + j * 256] = v[j];
    }
    __syncthreads();
#pragma unroll
    for (int r = 0; r < 16; ++r) {       // 128 m x 32 chunks (28 real)
        const int task = r * 256 + t;
        const int m = task >> 5, c8 = task & 31;
        if (c8 < 28) {
            bf16x8 w = *(const bf16x8*)&Ls[m * 256 + ((c8 ^ (m >> 3)) << 3)];
            *(bf16x8*)&G[(size_t)(b * 2048 + n0 + m) * 224 + c8 * 8] = w;
        }
    }
}

// ---------------- build W^T padded: WT[o][k] = (k<198 && o<Nout) ? W[k][o] : 0 ----------------
__global__ void build_wt(const float* __restrict__ W, __bf16* __restrict__ WT, int Nout) {
    const int id = blockIdx.x * 256 + threadIdx.x;   // 128*224
    if (id >= 128 * 224) return;
    const int o = id / 224, k = id % 224;
    WT[id] = (o < Nout && k < 198) ? (__bf16)W[(size_t)k * Nout + o] : (__bf16)0.f;
}

// ---------------- GEMM: C[M][Ncols] = A[M][K] @ B, B given as Bt[Ncols][K] ----------------
// 64x64 tile, BK=32, 256 threads = 4 waves (2x2), wave tile 32x32 = 2x2 mfma 16x16x32.
// epi: 0 outT[col][row] = bf16(acc)            (ld 2048)
//      1 outT[col][row] = bf16(2*acc - subT[col][row])
//      2 zrO[row*128+col] = bf16(sigmoid(acc + bias[col]))
//      3 outF[row*64+col] = r*state + (1-r)*tanh(acc+bias[col]), r = zrI[row*128+64+col]
__global__ __launch_bounds__(256, 4)
void gemm_bt(const __bf16* __restrict__ A, int lda,
             const __bf16* __restrict__ Bt, int ldb,
             int K, int epi,
             __bf16* __restrict__ outT, const __bf16* __restrict__ subT,
             float* __restrict__ outF, const float* __restrict__ bias,
             __bf16* __restrict__ zrO, const __bf16* __restrict__ zrI,
             const float* __restrict__ state) {
    __shared__ __bf16 As[64 * 32];
    __shared__ __bf16 Bs[64 * 32];
    const int t = threadIdx.x;
    const int l = t & 63, w = t >> 6;
    const int wr = w >> 1, wc = w & 1;
    const int m0 = blockIdx.x * 64;
    const int n0 = blockIdx.y * 64;
    const int lm = l & 15;
    const int lk = (l >> 4) * 8;
    const int srow = t >> 2;             // 0..63
    const int skc = (t & 3) * 8;

    f32x4 acc[2][2];
#pragma unroll
    for (int i = 0; i < 2; ++i)
#pragma unroll
        for (int j = 0; j < 2; ++j) acc[i][j] = (f32x4)0.f;

    const __bf16* Ab = A + (size_t)(m0 + srow) * lda + skc;
    const __bf16* Bb = Bt + (size_t)(n0 + srow) * ldb + skc;
    __bf16* AsD = As + t * 8;
    __bf16* BsD = Bs + t * 8;

    for (int k0 = 0; k0 < K; k0 += 32) {
        __builtin_amdgcn_global_load_lds(GLB(Ab + k0), LDS(AsD), 16, 0, 0);
        __builtin_amdgcn_global_load_lds(GLB(Bb + k0), LDS(BsD), 16, 0, 0);
        __syncthreads();
        bf16x8 af[2], bfr[2];
#pragma unroll
        for (int i = 0; i < 2; ++i)
            af[i] = *(const bf16x8*)(As + (wr * 32 + i * 16 + lm) * 32 + lk);
#pragma unroll
        for (int j = 0; j < 2; ++j)
            bfr[j] = *(const bf16x8*)(Bs + (wc * 32 + j * 16 + lm) * 32 + lk);
#pragma unroll
        for (int i = 0; i < 2; ++i)
#pragma unroll
            for (int j = 0; j < 2; ++j)
                acc[i][j] = __builtin_amdgcn_mfma_f32_16x16x32_bf16(af[i], bfr[j], acc[i][j], 0, 0, 0);
        __syncthreads();
    }

    // epilogue: C row = m (quad*4+reg), col = lane&15  [verified m89 layout]
    const int rb0 = m0 + wr * 32 + (l >> 4) * 4;
    const int cb0 = n0 + wc * 32 + lm;
#pragma unroll
    for (int i = 0; i < 2; ++i) {
        const int rbase = rb0 + i * 16;
#pragma unroll
        for (int j = 0; j < 2; ++j) {
            const int c = cb0 + j * 16;
            f32x4 v = acc[i][j];
            if (epi == 0) {
                bf16x4 pk;
#pragma unroll
                for (int r = 0; r < 4; ++r) pk[r] = (__bf16)v[r];
                *(bf16x4*)&outT[(size_t)c * 2048 + rbase] = pk;
            } else if (epi == 1) {
                bf16x4 s = *(const bf16x4*)&subT[(size_t)c * 2048 + rbase];
                bf16x4 pk;
#pragma unroll
                for (int r = 0; r < 4; ++r) pk[r] = (__bf16)(2.f * v[r] - (float)s[r]);
                *(bf16x4*)&outT[(size_t)c * 2048 + rbase] = pk;
            } else if (epi == 2) {
                const float bb = bias[c];
#pragma unroll
                for (int r = 0; r < 4; ++r) {
                    float xx = fminf(fmaxf(v[r] + bb, -30.f), 30.f);
                    zrO[(size_t)(rbase + r) * 128 + c] = (__bf16)(1.f / (1.f + __expf(-xx)));
                }
            } else {
                const float bb = bias[c];
#pragma unroll
                for (int r = 0; r < 4; ++r) {
                    const int m = rbase + r;
                    float xx = fminf(fmaxf(v[r] + bb, -15.f), 15.f);
                    float e = __expf(2.f * xx);
                    float hc = (e - 1.f) / (e + 1.f);
                    float rr = (float)zrI[(size_t)m * 128 + 64 + c];
                    float s = state[(size_t)m * 64 + c];
                    outF[(size_t)m * 64 + c] = rr * s + (1.f - rr) * hc;
                }
            }
        }
    }
}

extern "C" void kernel_launch(void* const* d_in, const int* in_sizes, int n_in,
                              void* d_out, int out_size, void* d_ws, size_t ws_size,
                              hipStream_t stream) {
    (void)in_sizes; (void)n_in; (void)out_size; (void)ws_size;
    const float* x  = (const float*)d_in[0];
    const float* st = (const float*)d_in[1];
    const float* E  = (const float*)d_in[2];
    const float* Wg = (const float*)d_in[3];
    const float* bg = (const float*)d_in[4];
    const float* Wu = (const float*)d_in[5];
    const float* bu = (const float*)d_in[6];
    float* out = (float*)d_out;

    char* p = (char*)d_ws;
    __bf16* S   = (__bf16*)p; p += (size_t)2048 * 2048 * 2;   // 8.4 MB
    __bf16* T0  = (__bf16*)p; p += (size_t)2112 * 2048 * 2;   // 8.65 MB
    __bf16* T1  = (__bf16*)p; p += (size_t)2112 * 2048 * 2;
    __bf16* T2  = (__bf16*)p; p += (size_t)2112 * 2048 * 2;
    __bf16* G   = (__bf16*)p; p += (size_t)65536 * 224 * 2;   // 29.4 MB
    __bf16* ZR  = (__bf16*)p; p += (size_t)65536 * 128 * 2;   // 16.8 MB
    __bf16* WTg = (__bf16*)p; p += 128 * 224 * 2;
    __bf16* WTu = (__bf16*)p; p += 128 * 224 * 2;             // total ~81 MB

    build_wt<<<112, 256, 0, stream>>>(Wg, WTg, 128);
    build_wt<<<112, 256, 0, stream>>>(Wu, WTu, 64);
    supports_kernel<<<2048, 256, 0, stream>>>(E, S);

    // gate phase
    build_t2<<<512, 256, 0, stream>>>(x, st, nullptr, T0);
    gemm_bt<<<dim3(32, 33), 256, 0, stream>>>(S, 2048, T0, 2048, 2048, 0, T1, nullptr, nullptr, nullptr, nullptr, nullptr, nullptr);
    gemm_bt<<<dim3(32, 33), 256, 0, stream>>>(S, 2048, T1, 2048, 2048, 1, T2, T0, nullptr, nullptr, nullptr, nullptr, nullptr);
    transpose_g<<<512, 256, 0, stream>>>(T0, T1, T2, G);
    gemm_bt<<<dim3(1024, 2), 256, 0, stream>>>(G, 224, WTg, 224, 224, 2, nullptr, nullptr, nullptr, bg, ZR, nullptr, nullptr);

    // update phase
    build_t2<<<512, 256, 0, stream>>>(x, st, ZR, T0);
    gemm_bt<<<dim3(32, 33), 256, 0, stream>>>(S, 2048, T0, 2048, 2048, 0, T1, nullptr, nullptr, nullptr, nullptr, nullptr, nullptr);
    gemm_bt<<<dim3(32, 33), 256, 0, stream>>>(S, 2048, T1, 2048, 2048, 1, T2, T0, nullptr, nullptr, nullptr, nullptr, nullptr);
    transpose_g<<<512, 256, 0, stream>>>(T0, T1, T2, G);
    gemm_bt<<<dim3(1024, 1), 256, 0, stream>>>(G, 224, WTu, 224, 224, 3, nullptr, nullptr, out, bu, nullptr, ZR, st);
}

// Round 4
// 297.281 us; speedup vs baseline: 1.4792x; 1.0557x over previous
//
#include <hip/hip_runtime.h>

// AGCRNCell on gfx950.  B=32, N=2048, C=66, CHEB_K=3, F=2112 (T padded to 2176 rows).
// R4: big GEMM 64x128 tile / 2 waves / wave-tile 64x64 (4x4 frags) / BK=64:
//     MFMA:LDS-byte ratio 2x of R3's 64x64 (R3 was LDS-throughput-bound at 14% MfmaUtil);
//     XOR-granule LDS swizzle (slot = g ^ (row&7)) -> conflict-free ds_read_b128
//     (staging permutes per-lane GLOBAL src; LDS dest stays base + lane*16);
//     G/WT K-padded to 256 so the W-GEMMs reuse the same kernel.

typedef __bf16 bf16x8 __attribute__((ext_vector_type(8)));
typedef __bf16 bf16x4 __attribute__((ext_vector_type(4)));
typedef float  f32x4  __attribute__((ext_vector_type(4)));

#define GLB(p) ((__attribute__((address_space(1))) void*)(void*)(p))
#define LDS(p) ((__attribute__((address_space(3))) void*)(p))

// ---------------- supports: S[n][m] = softmax_m(relu(E[n]·E[m])) ----------------
__global__ void supports_kernel(const float* __restrict__ E, __bf16* __restrict__ S) {
    const int n = blockIdx.x;
    const int t = threadIdx.x;            // 256
    const int l = t & 63, w = t >> 6;
    float en[10];
#pragma unroll
    for (int i = 0; i < 10; ++i) en[i] = E[n * 10 + i];
    float vals[8];
    float mx = 0.f;
#pragma unroll
    for (int q = 0; q < 8; ++q) {
        const int m = q * 256 + t;
        const float* em = E + (size_t)m * 10;
        float d = 0.f;
#pragma unroll
        for (int i = 0; i < 10; ++i) d += en[i] * em[i];
        d = fmaxf(d, 0.f);
        vals[q] = d;
        mx = fmaxf(mx, d);
    }
#pragma unroll
    for (int off = 32; off; off >>= 1) mx = fmaxf(mx, __shfl_xor(mx, off));
    __shared__ float sm[4], ss[4];
    if (l == 0) sm[w] = mx;
    __syncthreads();
    mx = fmaxf(fmaxf(sm[0], sm[1]), fmaxf(sm[2], sm[3]));
    float sum = 0.f;
#pragma unroll
    for (int q = 0; q < 8; ++q) { vals[q] = __expf(vals[q] - mx); sum += vals[q]; }
#pragma unroll
    for (int off = 32; off; off >>= 1) sum += __shfl_xor(sum, off);
    if (l == 0) ss[w] = sum;
    __syncthreads();
    sum = ss[0] + ss[1] + ss[2] + ss[3];
    const float inv = 1.f / sum;
#pragma unroll
    for (int q = 0; q < 8; ++q) S[(size_t)n * 2048 + q * 256 + t] = (__bf16)(vals[q] * inv);
}

// ---------------- zero pad rows f in [2112,2176) of T0 ----------------
__global__ void zero_pad(__bf16* __restrict__ Tpad) {
    const int id = blockIdx.x * 256 + threadIdx.x;   // 64*2048/8 = 16384 tasks
    bf16x8 z;
#pragma unroll
    for (int j = 0; j < 8; ++j) z[j] = (__bf16)0.f;
    *(bf16x8*)&Tpad[(size_t)id * 8] = z;
}

// ---------------- build T via LDS transpose: T[f=b*66+c][n], coalesced both sides ----
__global__ __launch_bounds__(256, 2)
void build_t2(const float* __restrict__ x, const float* __restrict__ st,
              const __bf16* __restrict__ zr, __bf16* __restrict__ T) {
    __shared__ float Ls[66 * 129];       // 34 KB
    const int b  = blockIdx.x >> 4;
    const int n0 = (blockIdx.x & 15) << 7;
    const int t = threadIdx.x;
    const size_t mb = (size_t)b * 2048 + n0;
    if (t < 128) {
        const float2 v = *(const float2*)&x[(mb + t) * 2];
        Ls[t] = v.x;
        Ls[129 + t] = v.y;
    }
#pragma unroll
    for (int r = 0; r < 8; ++r) {        // 128 rows x 16 col-quads
        const int task = r * 256 + t;
        const int q = task & 15, n = task >> 4;
        f32x4 v = *(const f32x4*)&st[(mb + n) * 64 + q * 4];
        if (zr) {
            const bf16x4 z = *(const bf16x4*)&zr[(mb + n) * 128 + q * 4];
#pragma unroll
            for (int j = 0; j < 4; ++j) v[j] *= (float)z[j];
        }
        const int base = (2 + q * 4) * 129 + n;
#pragma unroll
        for (int j = 0; j < 4; ++j) Ls[base + j * 129] = v[j];
    }
    __syncthreads();
#pragma unroll
    for (int r = 0; r < 5; ++r) {        // 66 c x 16 segs = 1056 tasks
        const int task = r * 256 + t;
        if (task < 1056) {
            const int c = task >> 4, seg = task & 15;
            const float* src = &Ls[c * 129 + seg * 8];
            bf16x8 o;
#pragma unroll
            for (int j = 0; j < 8; ++j) o[j] = (__bf16)src[j];
            *(bf16x8*)&T[(size_t)(b * 66 + c) * 2048 + n0 + seg * 8] = o;
        }
    }
}

// ---------------- transpose T-layout -> G[m=(b,n)][k], k padded to 256 ----------------
__global__ __launch_bounds__(256, 2)
void transpose_g(const __bf16* __restrict__ T0, const __bf16* __restrict__ T1,
                 const __bf16* __restrict__ T2, __bf16* __restrict__ G) {
    __shared__ __bf16 Ls[128 * 256];     // 64 KB
    const int b  = blockIdx.x >> 4;      // 0..31
    const int n0 = (blockIdx.x & 15) << 7;
    const int t = threadIdx.x;
#pragma unroll
    for (int r = 0; r < 16; ++r) {       // 256 k x 16 segs
        const int task = r * 256 + t;
        const int k = task >> 4, seg = task & 15;
        bf16x8 v;
        if (k < 198) {
            const __bf16* T; int c;
            if (k < 66)       { T = T0; c = k; }
            else if (k < 132) { T = T1; c = k - 66; }
            else              { T = T2; c = k - 132; }
            v = *(const bf16x8*)&T[(size_t)(b * 66 + c) * 2048 + n0 + seg * 8];
        } else {
#pragma unroll
            for (int j = 0; j < 8; ++j) v[j] = (__bf16)0.f;
        }
        const int base = seg * 8 * 256 + (((k >> 3) ^ seg) << 3) + (k & 7);
#pragma unroll
        for (int j = 0; j < 8; ++j) Ls[base + j * 256] = v[j];
    }
    __syncthreads();
#pragma unroll
    for (int r = 0; r < 16; ++r) {       // 128 m x 32 chunks
        const int task = r * 256 + t;
        const int m = task >> 5, c8 = task & 31;
        bf16x8 w = *(const bf16x8*)&Ls[m * 256 + ((c8 ^ (m >> 3)) << 3)];
        *(bf16x8*)&G[(size_t)(b * 2048 + n0 + m) * 256 + c8 * 8] = w;
    }
}

// ---------------- build W^T padded: WT[o][k] (128x256) ----------------
__global__ void build_wt(const float* __restrict__ W, __bf16* __restrict__ WT, int Nout) {
    const int id = blockIdx.x * 256 + threadIdx.x;   // 128*256
    const int o = id >> 8, k = id & 255;
    WT[id] = (o < Nout && k < 198) ? (__bf16)W[(size_t)k * Nout + o] : (__bf16)0.f;
}

// ---------------- GEMM: out[M][C] = A[M][K] @ B, B given as Bt[C][K] ----------------
// 64(m) x 128(c) tile, BK=64, 128 threads = 2 waves; each wave: all 64 m x 64 c,
// 4x4 frags of mfma 16x16x32. XOR-granule swizzled LDS (slot = g ^ (row&7)):
// conflict-free fragment ds_read_b128; staging permutes the per-lane global source.
// epi: 0 outT[c][m] = bf16(acc)            (ld 2048)
//      1 outT[c][m] = bf16(2*acc - subT[c][m])
//      2 zrO[m*128+c] = bf16(sigmoid(acc + bias[c]))
//      3 (c<64) outF[m*64+c] = r*state + (1-r)*tanh(acc+bias[c]), r = zrI[m*128+64+c]
__global__ __launch_bounds__(128, 3)
void gemm_s(const __bf16* __restrict__ A, int lda,
            const __bf16* __restrict__ Bt, int ldb,
            int K, int epi,
            __bf16* __restrict__ outT, const __bf16* __restrict__ subT,
            float* __restrict__ outF, const float* __restrict__ bias,
            __bf16* __restrict__ zrO, const __bf16* __restrict__ zrI,
            const float* __restrict__ state) {
    __shared__ __align__(16) __bf16 As[64 * 64];    //  8 KB
    __shared__ __align__(16) __bf16 Bs[128 * 64];   // 16 KB
    const int t = threadIdx.x;
    const int l = t & 63, w = t >> 6;
    const int lm = l & 15, kq = l >> 4;
    const int lm7 = lm & 7;
    const int m0 = blockIdx.x * 64;
    const int c0 = blockIdx.y * 128;
    const int sr = l >> 3;               // staging row-within-8
    const int gsw = (l & 7) ^ sr;        // swizzled source granule (fixed per lane)

    f32x4 acc[4][4];
#pragma unroll
    for (int i = 0; i < 4; ++i)
#pragma unroll
        for (int j = 0; j < 4; ++j) acc[i][j] = (f32x4)0.f;

    const __bf16* Asrc = A  + (size_t)(m0 + w * 32 + sr) * lda + gsw * 8;
    const __bf16* Bsrc = Bt + (size_t)(c0 + w * 64 + sr) * ldb + gsw * 8;
    __bf16* AsD = As + (w * 32) * 64 + l * 8;
    __bf16* BsD = Bs + (w * 64) * 64 + l * 8;

    for (int k0 = 0; k0 < K; k0 += 64) {
#pragma unroll
        for (int q = 0; q < 4; ++q)
            __builtin_amdgcn_global_load_lds(GLB(Asrc + (size_t)q * 8 * lda + k0),
                                             LDS(AsD + q * 8 * 64), 16, 0, 0);
#pragma unroll
        for (int q = 0; q < 8; ++q)
            __builtin_amdgcn_global_load_lds(GLB(Bsrc + (size_t)q * 8 * ldb + k0),
                                             LDS(BsD + q * 8 * 64), 16, 0, 0);
        __syncthreads();
#pragma unroll
        for (int ks = 0; ks < 2; ++ks) {
            const int ga = (((ks << 2) | kq) ^ lm7) << 3;
            bf16x8 af[4], bfr[4];
#pragma unroll
            for (int i = 0; i < 4; ++i)
                af[i] = *(const bf16x8*)(As + (i * 16 + lm) * 64 + ga);
#pragma unroll
            for (int j = 0; j < 4; ++j)
                bfr[j] = *(const bf16x8*)(Bs + (w * 64 + j * 16 + lm) * 64 + ga);
#pragma unroll
            for (int i = 0; i < 4; ++i)
#pragma unroll
                for (int j = 0; j < 4; ++j)
                    acc[i][j] = __builtin_amdgcn_mfma_f32_16x16x32_bf16(af[i], bfr[j], acc[i][j], 0, 0, 0);
        }
        __syncthreads();
    }

    // epilogue: C row = m (quad*4+reg), col = lane&15  [verified m89 layout]
    const int rb0 = m0 + kq * 4;
    const int cb0 = c0 + w * 64 + lm;
#pragma unroll
    for (int i = 0; i < 4; ++i) {
        const int rbase = rb0 + i * 16;
#pragma unroll
        for (int j = 0; j < 4; ++j) {
            const int c = cb0 + j * 16;
            f32x4 v = acc[i][j];
            if (epi == 0) {
                bf16x4 pk;
#pragma unroll
                for (int r = 0; r < 4; ++r) pk[r] = (__bf16)v[r];
                *(bf16x4*)&outT[(size_t)c * 2048 + rbase] = pk;
            } else if (epi == 1) {
                bf16x4 s = *(const bf16x4*)&subT[(size_t)c * 2048 + rbase];
                bf16x4 pk;
#pragma unroll
                for (int r = 0; r < 4; ++r) pk[r] = (__bf16)(2.f * v[r] - (float)s[r]);
                *(bf16x4*)&outT[(size_t)c * 2048 + rbase] = pk;
            } else if (epi == 2) {
                const float bb = bias[c];
#pragma unroll
                for (int r = 0; r < 4; ++r) {
                    float xx = fminf(fmaxf(v[r] + bb, -30.f), 30.f);
                    zrO[(size_t)(rbase + r) * 128 + c] = (__bf16)(1.f / (1.f + __expf(-xx)));
                }
            } else {
                if (c < 64) {
                    const float bb = bias[c];
#pragma unroll
                    for (int r = 0; r < 4; ++r) {
                        const int m = rbase + r;
                        float xx = fminf(fmaxf(v[r] + bb, -15.f), 15.f);
                        float e = __expf(2.f * xx);
                        float hc = (e - 1.f) / (e + 1.f);
                        float rr = (float)zrI[(size_t)m * 128 + 64 + c];
                        float s = state[(size_t)m * 64 + c];
                        outF[(size_t)m * 64 + c] = rr * s + (1.f - rr) * hc;
                    }
                }
            }
        }
    }
}

extern "C" void kernel_launch(void* const* d_in, const int* in_sizes, int n_in,
                              void* d_out, int out_size, void* d_ws, size_t ws_size,
                              hipStream_t stream) {
    (void)in_sizes; (void)n_in; (void)out_size; (void)ws_size;
    const float* x  = (const float*)d_in[0];
    const float* st = (const float*)d_in[1];
    const float* E  = (const float*)d_in[2];
    const float* Wg = (const float*)d_in[3];
    const float* bg = (const float*)d_in[4];
    const float* Wu = (const float*)d_in[5];
    const float* bu = (const float*)d_in[6];
    float* out = (float*)d_out;

    char* p = (char*)d_ws;
    __bf16* S   = (__bf16*)p; p += (size_t)2048 * 2048 * 2;   // 8.4 MB
    __bf16* T0  = (__bf16*)p; p += (size_t)2176 * 2048 * 2;   // 8.9 MB
    __bf16* T1  = (__bf16*)p; p += (size_t)2176 * 2048 * 2;
    __bf16* T2  = (__bf16*)p; p += (size_t)2176 * 2048 * 2;
    __bf16* G   = (__bf16*)p; p += (size_t)65536 * 256 * 2;   // 33.6 MB
    __bf16* ZR  = (__bf16*)p; p += (size_t)65536 * 128 * 2;   // 16.8 MB
    __bf16* WTg = (__bf16*)p; p += 128 * 256 * 2;
    __bf16* WTu = (__bf16*)p; p += 128 * 256 * 2;             // ~86 MB

    build_wt<<<128, 256, 0, stream>>>(Wg, WTg, 128);
    build_wt<<<128, 256, 0, stream>>>(Wu, WTu, 64);
    zero_pad<<<64, 256, 0, stream>>>(T0 + (size_t)2112 * 2048);
    supports_kernel<<<2048, 256, 0, stream>>>(E, S);

    // gate phase
    build_t2<<<512, 256, 0, stream>>>(x, st, nullptr, T0);
    gemm_s<<<dim3(32, 17), 128, 0, stream>>>(S, 2048, T0, 2048, 2048, 0, T1, nullptr, nullptr, nullptr, nullptr, nullptr, nullptr);
    gemm_s<<<dim3(32, 17), 128, 0, stream>>>(S, 2048, T1, 2048, 2048, 1, T2, T0, nullptr, nullptr, nullptr, nullptr, nullptr);
    transpose_g<<<512, 256, 0, stream>>>(T0, T1, T2, G);
    gemm_s<<<dim3(1024, 1), 128, 0, stream>>>(G, 256, WTg, 256, 256, 2, nullptr, nullptr, nullptr, bg, ZR, nullptr, nullptr);

    // update phase
    build_t2<<<512, 256, 0, stream>>>(x, st, ZR, T0);
    gemm_s<<<dim3(32, 17), 128, 0, stream>>>(S, 2048, T0, 2048, 2048, 0, T1, nullptr, nullptr, nullptr, nullptr, nullptr, nullptr);
    gemm_s<<<dim3(32, 17), 128, 0, stream>>>(S, 2048, T1, 2048, 2048, 1, T2, T0, nullptr, nullptr, nullptr, nullptr, nullptr);
    transpose_g<<<512, 256, 0, stream>>>(T0, T1, T2, G);
    gemm_s<<<dim3(1024, 1), 128, 0, stream>>>(G, 256, WTu, 256, 256, 3, nullptr, nullptr, out, bu, nullptr, ZR, st);
}